// Round 11
// baseline (473.661 us; speedup 1.0000x reference)
//
#include <hip/hip_runtime.h>
#include <hip/hip_bf16.h>
#include <math.h>
#include <stdint.h>

#define N_NODES 50000
#define N_EDGES 800000
#define HID 128
#define NGRAPH 256
#define NLAYER 2
#define CAP 64  // CSR slots per node; Poisson(16) tail beyond 64 ~ 1e-18

// Atomic-free CSR build, v3: 98 binning blocks x 1024 threads each own 512
// consecutive targets (128KB LDS slab, 1 block/CU), scan a u16-packed tgt
// array (1.6MB; 8 edges per 16B load). Scan redundancy = 98 x 1.6MB = 157MB
// (R10: 196 x 3.2MB = 627MB -> 107us). Zero global atomics (R8: atomic
// scatter = ~100MB line-RMW traffic ~= 55us floor).
#define BIN_B 98                      // ceil(50000/512) binning blocks
#define BIN_T 512                     // targets per block
#define N_PAD (BIN_B * BIN_T)         // 50176: ei rows padded to full blocks

// prep1 sections (1024-thread blocks): binning | encoder | tkv
#define ENC_B 782                     // encoder: 800000 ch-groups / 1024
#define TKV_B 256                     // 1024 (l,md) rows / 4 per block
#define PREP1_B (BIN_B + ENC_B + TKV_B)

// prep0 sections (256-thread blocks): repack (128) | setup (4) | pack (782)
#define PREP0_B (132 + 782)

typedef __bf16 bf16x8 __attribute__((ext_vector_type(8)));
typedef __bf16 bf16x2 __attribute__((ext_vector_type(2)));
typedef float f32x4 __attribute__((ext_vector_type(4)));
typedef float f32x2 __attribute__((ext_vector_type(2)));

__device__ __forceinline__ float gelu_f(float v) {
    return 0.5f * v * (1.0f + erff(v * 0.70710678118654752f));
}

// fp8 e4m3 (OCP on gfx950) helpers — cvt_pk returns a natural f32 pair
__device__ __forceinline__ f32x2 f8lo(uint32_t d) {
    return __builtin_amdgcn_cvt_pk_f32_fp8((int)d, false);
}
__device__ __forceinline__ f32x2 f8hi(uint32_t d) {
    return __builtin_amdgcn_cvt_pk_f32_fp8((int)d, true);
}
__device__ __forceinline__ uint32_t pk4_fp8(float a, float b, float c, float d) {
    int w = __builtin_amdgcn_cvt_pk_fp8_f32(a, b, 0, false);
    w = __builtin_amdgcn_cvt_pk_fp8_f32(c, d, w, true);
    return (uint32_t)w;
}
// bf16 pair (one dword) -> f32 pair. lo: shift. hi: reinterpret the dword
// directly — low 16 garbage bits contribute < 1 bf16 ulp.
__device__ __forceinline__ f32x2 bfpair(uint32_t d) {
    f32x2 r;
    r[0] = __uint_as_float(d << 16);
    r[1] = __uint_as_float(d);
    return r;
}

// ---------------- prep0: weight repack | setup | edge payload+tgt16 pack ---------
__global__ __launch_bounds__(256) void prep0_kernel(
    const float* __restrict__ Wq, const float* __restrict__ Wa,
    const float* __restrict__ Wmid, const float* __restrict__ Wo,
    const float* __restrict__ Wk, const float* __restrict__ Wv,
    __bf16* __restrict__ wqkvf, __bf16* __restrict__ waf,
    __bf16* __restrict__ wmidf, __bf16* __restrict__ wof,
    const int* __restrict__ batch, const float* __restrict__ bout,
    const float* __restrict__ bq, const float* __restrict__ bk,
    const float* __restrict__ bv,
    float* __restrict__ invc, float* __restrict__ outp, float* __restrict__ bqkv,
    const int* __restrict__ src, const int* __restrict__ sd,
    const int* __restrict__ sp, const int* __restrict__ tgt,
    uint32_t* __restrict__ pack, uint16_t* __restrict__ t16) {
    int b = blockIdx.x;
    int tid = threadIdx.x;
    if (b < 128) {
        // ---- weight repack: fp32 [CI][CO] -> bf16 fragment units, sigma perm ----
        int u = b * 256 + tid;
        int l = u >> 14, r = u & 16383;
        const float* srcp;
        __bf16* dstp;
        int kg, scol, srcCO;
        if (r < 6144) {  // fused QKV, CO=384
            kg = r / 384;
            int uu = r % 384;
            int sec = uu >> 7, cc = uu & 127;
            scol = ((cc & 15) << 3) | (cc >> 4);
            const float* Ws = (sec == 0) ? Wq : (sec == 1) ? Wk : Wv;
            srcp = Ws + l * 16384;
            srcCO = 128;
            dstp = wqkvf + (size_t)l * 49152 + (size_t)r * 8;
        } else if (r < 8192) {  // Wa
            int rr = r - 6144;
            kg = rr >> 7;
            int cc = rr & 127;
            scol = ((cc & 15) << 3) | (cc >> 4);
            srcp = Wa + l * 16384;
            srcCO = 128;
            dstp = waf + (size_t)l * 16384 + (size_t)rr * 8;
        } else if (r < 12288) {  // Wmid, CO=256
            int rr = r - 8192;
            kg = rr >> 8;
            int uu = rr & 255;
            int blk = uu >> 7, cc = uu & 127;
            scol = blk * 128 + (((cc & 15) << 3) | (cc >> 4));
            srcp = Wmid + l * 32768;
            srcCO = 256;
            dstp = wmidf + (size_t)l * 32768 + (size_t)rr * 8;
        } else {  // Wo, CI=256
            int rr = r - 12288;
            kg = rr >> 7;
            int cc = rr & 127;
            scol = ((cc & 15) << 3) | (cc >> 4);
            srcp = Wo + l * 32768;
            srcCO = 128;
            dstp = wof + (size_t)l * 32768 + (size_t)rr * 8;
        }
        bf16x8 o;
#pragma unroll
        for (int j = 0; j < 8; j++) o[j] = (__bf16)srcp[(kg * 8 + j) * srcCO + scol];
        *(bf16x8*)dstp = o;
    } else if (b < 132) {
        // ---- setup: per-graph invc + out init, fused QKV bias ----
        int sb = b - 128;
        if (sb == 0) {
            int g = tid;
            int lo = 0, hi = N_NODES;
            while (lo < hi) { int mid = (lo + hi) >> 1; if (batch[mid] < g) lo = mid + 1; else hi = mid; }
            int start = lo;
            lo = start; hi = N_NODES;
            while (lo < hi) { int mid = (lo + hi) >> 1; if (batch[mid] < g + 1) lo = mid + 1; else hi = mid; }
            int c2 = lo - start;
            invc[g] = 1.0f / fmaxf((float)c2, 1.0f);
            outp[g] = bout[0];
        } else {
            int r = (sb - 1) * 256 + tid;
            int l = r / 384, c = r % 384;
            float v = (c < 128) ? bq[l * 128 + c]
                    : (c < 256) ? bk[l * 128 + c - 128]
                                : bv[l * 128 + c - 256];
            bqkv[r] = v;
        }
    } else {
        // ---- edge pack: pack[e] = src|((sd<<4|sp)<<16); t16[e] = (u16)tgt[e] ----
        int e0 = (b - 132) * 1024 + tid * 4;
        if (e0 + 3 < N_EDGES) {
            int4 s4 = *(const int4*)(src + e0);
            int4 d4 = *(const int4*)(sd + e0);
            int4 p4 = *(const int4*)(sp + e0);
            int4 t4 = *(const int4*)(tgt + e0);
            uint4 o;
            o.x = (uint32_t)s4.x | ((uint32_t)((d4.x << 4) | p4.x) << 16);
            o.y = (uint32_t)s4.y | ((uint32_t)((d4.y << 4) | p4.y) << 16);
            o.z = (uint32_t)s4.z | ((uint32_t)((d4.z << 4) | p4.z) << 16);
            o.w = (uint32_t)s4.w | ((uint32_t)((d4.w << 4) | p4.w) << 16);
            *(uint4*)(pack + e0) = o;
            uint2 tt;
            tt.x = (uint32_t)t4.x | ((uint32_t)t4.y << 16);
            tt.y = (uint32_t)t4.z | ((uint32_t)t4.w << 16);
            *(uint2*)(t16 + e0) = tt;
        }
    }
}

// ---------------- prep1: u16-scan CSR binning | encoder | tkv (1024 thr) ---------
__global__ __launch_bounds__(1024) void prep1_kernel(
    const int* __restrict__ attr, const float* __restrict__ aemb,
    __bf16* __restrict__ xb,
    const float* __restrict__ de, const float* __restrict__ pe,
    const float* __restrict__ Wk, const float* __restrict__ Wv,
    __bf16* __restrict__ tkv,
    const uint16_t* __restrict__ t16, const uint32_t* __restrict__ pack,
    int* __restrict__ cnt, uint32_t* __restrict__ ei) {
    __shared__ int lcnt[BIN_T];
    __shared__ uint32_t lei[BIN_T * CAP];  // 128 KB LDS CSR slab
    __shared__ float sde[4][128];
    int b = blockIdx.x;
    int tid = threadIdx.x;
    if (b < BIN_B) {
        // ---- CSR binning: this block owns targets [b*512, b*512+512) ----
        unsigned lo = (unsigned)(b << 9);
        if (tid < BIN_T) lcnt[tid] = 0;
        __syncthreads();
        // scan u16 targets: 8192 edges/iter (1024 thr x 8), 4-way unrolled
        for (int it0 = 0; it0 < 96; it0 += 4) {
            uint4 w4[4];
#pragma unroll
            for (int u = 0; u < 4; u++)
                w4[u] = *(const uint4*)(t16 + (it0 + u) * 8192 + tid * 8);
#pragma unroll
            for (int u = 0; u < 4; u++) {
                int e0 = (it0 + u) * 8192 + tid * 8;
                uint32_t dws[4] = {w4[u].x, w4[u].y, w4[u].z, w4[u].w};
#pragma unroll
                for (int j = 0; j < 4; j++) {
                    unsigned ta = (dws[j] & 0xffffu) - lo;
                    unsigned tb = (dws[j] >> 16) - lo;
                    if (ta < (unsigned)BIN_T) {
                        int r = atomicAdd(&lcnt[ta], 1);  // LDS atomic: cheap
                        if (r < CAP) lei[(ta << 6) + r] = pack[e0 + 2 * j];
                    }
                    if (tb < (unsigned)BIN_T) {
                        int r = atomicAdd(&lcnt[tb], 1);
                        if (r < CAP) lei[(tb << 6) + r] = pack[e0 + 2 * j + 1];
                    }
                }
            }
        }
        for (int it = 96; it < 98; ++it) {  // 786432..800000 tail (multiple of 8)
            int e0 = it * 8192 + tid * 8;
            if (e0 + 7 < N_EDGES) {
                uint4 w = *(const uint4*)(t16 + e0);
                uint32_t dws[4] = {w.x, w.y, w.z, w.w};
#pragma unroll
                for (int j = 0; j < 4; j++) {
                    unsigned ta = (dws[j] & 0xffffu) - lo;
                    unsigned tb = (dws[j] >> 16) - lo;
                    if (ta < (unsigned)BIN_T) {
                        int r = atomicAdd(&lcnt[ta], 1);
                        if (r < CAP) lei[(ta << 6) + r] = pack[e0 + 2 * j];
                    }
                    if (tb < (unsigned)BIN_T) {
                        int r = atomicAdd(&lcnt[tb], 1);
                        if (r < CAP) lei[(tb << 6) + r] = pack[e0 + 2 * j + 1];
                    }
                }
            }
        }
        __syncthreads();
        // write out: cnt + 128KB ei slab, fully coalesced (no memset anywhere)
        if (tid < BIN_T) {
            int t = (int)lo + tid;
            if (t < N_NODES) cnt[t] = min(lcnt[tid], CAP);
        }
        uint32_t* gout = ei + ((size_t)lo << 6);
#pragma unroll
        for (int i2 = 0; i2 < 8; ++i2) {
            int w = i2 * 4096 + tid * 4;
            *(uint4*)(gout + w) = *(const uint4*)(lei + w);
        }
        return;
    }
    b -= BIN_B;
    if (b < ENC_B) {
        // ---- node encoder: 8 channels/thread, float4 table reads ----
        int gid = b * 1024 + tid;     // [0, 800000) = 50000 nodes * 16 groups
        if (gid < N_NODES * 16) {
            int n = gid >> 4;
            int c8 = (gid & 15) << 3;
            const int4 a = *(const int4*)(attr + n * 4);
            const float* r0 = aemb + (size_t)(0 * 64 + a.x) * 128 + c8;
            const float* r1 = aemb + (size_t)(1 * 64 + a.y) * 128 + c8;
            const float* r2 = aemb + (size_t)(2 * 64 + a.z) * 128 + c8;
            const float* r3 = aemb + (size_t)(3 * 64 + a.w) * 128 + c8;
            f32x4 v0a = *(const f32x4*)r0, v0b = *(const f32x4*)(r0 + 4);
            f32x4 v1a = *(const f32x4*)r1, v1b = *(const f32x4*)(r1 + 4);
            f32x4 v2a = *(const f32x4*)r2, v2b = *(const f32x4*)(r2 + 4);
            f32x4 v3a = *(const f32x4*)r3, v3b = *(const f32x4*)(r3 + 4);
            bf16x8 o;
#pragma unroll
            for (int j = 0; j < 4; j++) {
                o[j] = (__bf16)(v0a[j] + v1a[j] + v2a[j] + v3a[j]);
                o[4 + j] = (__bf16)(v0b[j] + v1b[j] + v2b[j] + v3b[j]);
            }
            *(bf16x8*)(xb + (size_t)n * 128 + c8) = o;
        }
    } else {
        // ---- combined relational tables: 4 (l,md) rows per 1024-thr block ----
        int bb = (b - ENC_B) * 4 + (tid >> 8);  // [0, 1024)
        int c = tid & 255;
        int l = bb >> 9;
        int md = bb & 511;
        int dd = md >> 4, pp = md & 15;
        int g = tid >> 8;
        if (c < 128) sde[g][c] = de[l * 4096 + dd * 128 + c] + pe[l * 2048 + pp * 128 + c];
        __syncthreads();
        const float* W = (c < 128) ? (Wk + l * 16384) : (Wv + l * 16384);
        int cc = c & 127;
        float acc = 0.f;
#pragma unroll 4
        for (int k = 0; k < 128; k++) acc = fmaf(sde[g][k], W[k * 128 + cc], acc);
        tkv[(size_t)bb * 256 + c] = (__bf16)acc;
    }
}

// ---------------- QKV GEMM (pure) -------------------------------------------------
__global__ __launch_bounds__(256) void qkv_gemm(
    const __bf16* __restrict__ A, const __bf16* __restrict__ Wf,
    const float* __restrict__ bias, __bf16* __restrict__ Qb,
    uint8_t* __restrict__ kv8, int M) {
    int tid = threadIdx.x;
    int bq = blockIdx.x;
    int sec = bq % 3;           // consecutive blocks share A rows -> L2 reuse
    int rowblk = bq / 3;
    int lane = tid & 63;
    int wv = tid >> 6;
    int row0 = rowblk * 64 + wv * 16;
    int col0 = sec * 128;
    if (row0 >= M) return;
    int quad = lane >> 4, tq = lane & 15;
    f32x4 acc[8] = {};
#pragma unroll
    for (int k0 = 0; k0 < 128; k0 += 32) {
        int rr = row0 + tq;
        if (rr >= M) rr = M - 1;
        bf16x8 af = *(const bf16x8*)(A + (size_t)rr * 128 + k0 + quad * 8);
#pragma unroll
        for (int nt = 0; nt < 8; nt++) {
            bf16x8 bfr = *(const bf16x8*)(Wf + ((size_t)((k0 >> 3) + quad) * 384 + col0 + nt * 16 + tq) * 8);
            acc[nt] = __builtin_amdgcn_mfma_f32_16x16x32_bf16(af, bfr, acc[nt], 0, 0, 0);
        }
    }
    int cb = tq * 8;
    float bia[8];
#pragma unroll
    for (int t = 0; t < 8; t++) bia[t] = bias[col0 + cb + t];
#pragma unroll
    for (int v = 0; v < 4; v++) {
        int rr = row0 + quad * 4 + v;
        if (rr >= M) continue;
        float val[8];
#pragma unroll
        for (int t = 0; t < 8; t++) val[t] = acc[t][v] + bia[t];
        if (sec == 0) {
            bf16x8 ov;
#pragma unroll
            for (int t = 0; t < 8; t++) ov[t] = (__bf16)val[t];
            *(bf16x8*)(Qb + (size_t)rr * 128 + cb) = ov;
        } else {
            uint2 st;
            st.x = pk4_fp8(val[0], val[1], val[2], val[3]);
            st.y = pk4_fp8(val[4], val[5], val[6], val[7]);
            *(uint2*)(kv8 + (size_t)rr * 256 + (sec - 1) * 128 + cb) = st;
        }
    }
}

// ---------------- uber FFN: h=LN1(aggr@Wa+ba+x); mid=gelu(h@Wmid); x=LN2(mid@Wo+h)
template <bool POOL>
__global__ __launch_bounds__(256) void ffn_uber(
    const __bf16* __restrict__ A,      // gelu(aggr), N x 128
    const __bf16* __restrict__ xres,   // x (LN1 residual), N x 128
    const __bf16* __restrict__ Waf, const float* __restrict__ ba,
    const float* __restrict__ l1g, const float* __restrict__ l1b,
    const __bf16* __restrict__ Wmf, const float* __restrict__ bmid,
    const __bf16* __restrict__ Wof, const float* __restrict__ bo,
    const float* __restrict__ l2g, const float* __restrict__ l2b,
    __bf16* __restrict__ outx,
    const int* __restrict__ batch, const float* __restrict__ invc,
    const float* __restrict__ WoutV, float* __restrict__ outp,
    int M) {
    __shared__ __bf16 hld[4][16][136];   // per-wave 16x128 h tile, +8 row pad
    __shared__ __bf16 smid[4][16][264];  // per-wave 16x256 mid tile, +8 row pad
    __shared__ float ps[POOL ? NGRAPH : 1];
    int lane = threadIdx.x & 63;
    int wv = threadIdx.x >> 6;
    int row0 = blockIdx.x * 64 + wv * 16;
    bool active = row0 < M;
    if (POOL) {
        ps[threadIdx.x] = 0.f;
        __syncthreads();
    } else if (!active) {
        return;
    }
    int quad = lane >> 4, tq = lane & 15;
    if (active) {
        int cb = tq * 8;
        // ---- phase 0: h = LN1(aggr@Wa + ba + x) -> hld ----
        {
            f32x4 acc[8] = {};
#pragma unroll
            for (int k0 = 0; k0 < 128; k0 += 32) {
                int rr = row0 + tq;
                if (rr >= M) rr = M - 1;
                bf16x8 af = *(const bf16x8*)(A + (size_t)rr * 128 + k0 + quad * 8);
#pragma unroll
                for (int nt = 0; nt < 8; nt++) {
                    bf16x8 bfr = *(const bf16x8*)(Waf + ((size_t)((k0 >> 3) + quad) * 128 + nt * 16 + tq) * 8);
                    acc[nt] = __builtin_amdgcn_mfma_f32_16x16x32_bf16(af, bfr, acc[nt], 0, 0, 0);
                }
            }
            float bia[8], gv[8], bv2[8];
#pragma unroll
            for (int t = 0; t < 8; t++) {
                bia[t] = ba[cb + t];
                gv[t] = l1g[cb + t];
                bv2[t] = l1b[cb + t];
            }
#pragma unroll
            for (int v = 0; v < 4; v++) {
                int rr = row0 + quad * 4 + v;
                int rc = (rr < M) ? rr : M - 1;
                bf16x8 rv = *(const bf16x8*)(xres + (size_t)rc * 128 + cb);
                float val[8];
#pragma unroll
                for (int t = 0; t < 8; t++) val[t] = acc[t][v] + bia[t] + (float)rv[t];
                float s = 0.f, s2 = 0.f;
#pragma unroll
                for (int t = 0; t < 8; t++) { s += val[t]; s2 = fmaf(val[t], val[t], s2); }
#pragma unroll
                for (int o = 1; o < 16; o <<= 1) {
                    s += __shfl_xor(s, o);
                    s2 += __shfl_xor(s2, o);
                }
                float m = s * (1.0f / 128.0f);
                float var = s2 * (1.0f / 128.0f) - m * m;
                float rs = rsqrtf(var + 1e-5f);
                bf16x8 ov;
#pragma unroll
                for (int t = 0; t < 8; t++) ov[t] = (__bf16)((val[t] - m) * rs * gv[t] + bv2[t]);
                *(bf16x8*)(&hld[wv][quad * 4 + v][cb]) = ov;
            }
        }
        asm volatile("" ::: "memory");  // keep ds_reads after ds_writes (in-order DS)
        // ---- phase 1: mid = gelu(h@Wmid + bmid) -> smid ----
#pragma unroll
        for (int cH = 0; cH < 2; ++cH) {
            f32x4 acc[8] = {};
#pragma unroll
            for (int k0 = 0; k0 < 128; k0 += 32) {
                bf16x8 af = *(const bf16x8*)(&hld[wv][tq][k0 + quad * 8]);
#pragma unroll
                for (int nt = 0; nt < 8; nt++) {
                    bf16x8 bfr = *(const bf16x8*)(Wmf + ((size_t)((k0 >> 3) + quad) * 256 + cH * 128 + nt * 16 + tq) * 8);
                    acc[nt] = __builtin_amdgcn_mfma_f32_16x16x32_bf16(af, bfr, acc[nt], 0, 0, 0);
                }
            }
            int cb2 = cH * 128 + cb;
            float bia[8];
#pragma unroll
            for (int t = 0; t < 8; t++) bia[t] = bmid[cb2 + t];
#pragma unroll
            for (int v = 0; v < 4; v++) {
                bf16x8 ov;
#pragma unroll
                for (int t = 0; t < 8; t++) ov[t] = (__bf16)gelu_f(acc[t][v] + bia[t]);
                *(bf16x8*)(&smid[wv][quad * 4 + v][cb2]) = ov;
            }
        }
        asm volatile("" ::: "memory");
        // ---- phase 2: x = LN2(mid@Wo + bo + h) ----
        f32x4 acc[8] = {};
#pragma unroll
        for (int k0 = 0; k0 < 256; k0 += 32) {
            bf16x8 af = *(const bf16x8*)(&smid[wv][tq][k0 + quad * 8]);
#pragma unroll
            for (int nt = 0; nt < 8; nt++) {
                bf16x8 bfr = *(const bf16x8*)(Wof + ((size_t)((k0 >> 3) + quad) * 128 + nt * 16 + tq) * 8);
                acc[nt] = __builtin_amdgcn_mfma_f32_16x16x32_bf16(af, bfr, acc[nt], 0, 0, 0);
            }
        }
        float bia[8], gv[8], bv2[8], wo8[8];
#pragma unroll
        for (int t = 0; t < 8; t++) {
            bia[t] = bo[cb + t];
            gv[t] = l2g[cb + t];
            bv2[t] = l2b[cb + t];
        }
        if (POOL) {
#pragma unroll
            for (int t = 0; t < 8; t++) wo8[t] = WoutV[cb + t];
        }
#pragma unroll
        for (int v = 0; v < 4; v++) {
            int rr = row0 + quad * 4 + v;
            bf16x8 rv = *(const bf16x8*)(&hld[wv][quad * 4 + v][cb]);  // residual h
            float val[8];
#pragma unroll
            for (int t = 0; t < 8; t++) val[t] = acc[t][v] + bia[t] + (float)rv[t];
            float s = 0.f, s2 = 0.f;
#pragma unroll
            for (int t = 0; t < 8; t++) { s += val[t]; s2 = fmaf(val[t], val[t], s2); }
#pragma unroll
            for (int o = 1; o < 16; o <<= 1) {
                s += __shfl_xor(s, o);
                s2 += __shfl_xor(s2, o);
            }
            float m = s * (1.0f / 128.0f);
            float var = s2 * (1.0f / 128.0f) - m * m;
            float rs = rsqrtf(var + 1e-5f);
#pragma unroll
            for (int t = 0; t < 8; t++) val[t] = (val[t] - m) * rs * gv[t] + bv2[t];
            if (rr >= M) continue;
            if (!POOL) {
                bf16x8 ov;
#pragma unroll
                for (int t = 0; t < 8; t++) ov[t] = (__bf16)val[t];
                *(bf16x8*)(outx + (size_t)rr * 128 + cb) = ov;
            } else {
                float dot = 0.f;
#pragma unroll
                for (int t = 0; t < 8; t++) dot = fmaf(val[t], wo8[t], dot);
#pragma unroll
                for (int o = 1; o < 16; o <<= 1) dot += __shfl_xor(dot, o);
                if (tq == 0) {
                    int g = batch[rr];
                    atomicAdd(&ps[g], dot * invc[g]);  // LDS atomic: fast, per-CU
                }
            }
        }
    }
    if (POOL) {
        __syncthreads();
        float pv = ps[threadIdx.x];
        if (pv != 0.f) atomicAdd(&outp[threadIdx.x], pv);
    }
}

// ---------------- attention: one wave per node, 8 edges in flight, 1 head/lane ----
// CAP-CSR; fp8 K/V; bf16 tkv; 2-deep pipeline; packed-f32 (v_pk_*) inner math.
// HEADS=8, DK=16: each lane's 16 channels = one full head -> per-head softmax.
__global__ __launch_bounds__(256) void attn_kernel(
    const __bf16* __restrict__ Qb, const uint8_t* __restrict__ kv8,
    const __bf16* __restrict__ tkv,
    const int* __restrict__ cnt, const uint32_t* __restrict__ ei,
    __bf16* __restrict__ outb) {
    __shared__ float red[4][1376];  // 8 slots x 172 words per wave
    int wv = threadIdx.x >> 6;
    int i = blockIdx.x * 4 + wv;  // N = 50000 = 12500*4: no tail
    int lane = threadIdx.x & 63;
    int slot = lane >> 3, h = lane & 7;
    int ch0 = h * 16;
    // q as 8 packed f32 pairs (fixed cost, out of loop)
    const uint4* qv = (const uint4*)(Qb + (size_t)i * 128 + ch0);
    uint4 qa = qv[0], qb = qv[1];
    uint32_t qd[8] = {qa.x, qa.y, qa.z, qa.w, qb.x, qb.y, qb.z, qb.w};
    f32x2 qp[8];
#pragma unroll
    for (int j = 0; j < 8; j++) qp[j] = bfpair(qd[j]);
    int deg = cnt[i];
    if (deg > CAP) deg = CAP;
    int p0 = i << 6;
    int p1 = p0 + deg;
    float l = 0.f;
    f32x2 ap[8] = {};
    int p = p0 + slot;
    uint32_t w1 = 0, w2 = 0;
    if (p < p1) w1 = ei[p];
    if (p + 8 < p1) w2 = ei[p + 8];
    uint4 kw, vw, t0, t1, u0, u1;
    {
        int j = w1 & 0xffff, md = w1 >> 16;
        const uint8_t* kr = kv8 + (size_t)j * 256 + ch0;
        kw = *(const uint4*)kr;
        vw = *(const uint4*)(kr + 128);
        const __bf16* tr = tkv + md * 256 + ch0;
        t0 = *(const uint4*)tr;
        t1 = *(const uint4*)(tr + 8);
        u0 = *(const uint4*)(tr + 128);
        u1 = *(const uint4*)(tr + 136);
    }
    while (p < p1) {
        uint4 kwn, vwn, t0n, t1n, u0n, u1n;
        {
            int j = w2 & 0xffff, md = w2 >> 16;
            const uint8_t* kr = kv8 + (size_t)j * 256 + ch0;
            kwn = *(const uint4*)kr;
            vwn = *(const uint4*)(kr + 128);
            const __bf16* tr = tkv + md * 256 + ch0;
            t0n = *(const uint4*)tr;
            t1n = *(const uint4*)(tr + 8);
            u0n = *(const uint4*)(tr + 128);
            u1n = *(const uint4*)(tr + 136);
        }
        // unconditional clamped prefetch (no exec-mask branch in the loop)
        int pn = p + 16;
        uint32_t w3 = ei[(pn < p1) ? pn : p];
        uint32_t kd[4] = {kw.x, kw.y, kw.z, kw.w};
        uint32_t vd[4] = {vw.x, vw.y, vw.z, vw.w};
        uint32_t td[8] = {t0.x, t0.y, t0.z, t0.w, t1.x, t1.y, t1.z, t1.w};
        uint32_t ud[8] = {u0.x, u0.y, u0.z, u0.w, u1.x, u1.y, u1.z, u1.w};
        f32x2 sa = {0.f, 0.f};
#pragma unroll
        for (int j = 0; j < 4; j++) {
            f32x2 klo = f8lo(kd[j]) + bfpair(td[2 * j]);
            f32x2 khi = f8hi(kd[j]) + bfpair(td[2 * j + 1]);
            sa = qp[2 * j] * klo + sa;       // v_pk_fma_f32
            sa = qp[2 * j + 1] * khi + sa;
        }
        float s = sa[0] + sa[1];
        float pe = __expf(s * 0.25f);  // 1/sqrt(DK)
        l += pe;
        f32x2 pp = {pe, pe};
#pragma unroll
        for (int j = 0; j < 4; j++) {
            f32x2 vlo = f8lo(vd[j]) + bfpair(ud[2 * j]);
            f32x2 vhi = f8hi(vd[j]) + bfpair(ud[2 * j + 1]);
            ap[2 * j] = pp * vlo + ap[2 * j];
            ap[2 * j + 1] = pp * vhi + ap[2 * j + 1];
        }
        kw = kwn; vw = vwn; t0 = t0n; t1 = t1n; u0 = u0n; u1 = u1n;
        w2 = w3;
        p += 8;
    }
    // ---- LDS slot-merge epilogue (same-wave produce/consume: no barrier) ----
    float* rw = red[wv] + slot * 172 + 20 * h;  // pad(16h) = 20h
#pragma unroll
    for (int j = 0; j < 8; j++) *(f32x2*)(rw + 2 * j) = ap[j];
    red[wv][slot * 172 + 156 + h] = l;
    asm volatile("" ::: "memory");  // keep ds_reads after ds_writes (DS in-order per wave)
    int pc = 2 * lane + 4 * (lane >> 3);  // pad(2*lane)
    int hh = lane >> 3;
    float s0 = 0.f, s1 = 0.f, ls = 0.f;
#pragma unroll
    for (int s = 0; s < 8; s++) {
        float2 v = *(const float2*)(red[wv] + s * 172 + pc);
        s0 += v.x;
        s1 += v.y;
        ls += red[wv][s * 172 + 156 + hh];
    }
    float inv = 1.0f / (ls + 1e-16f);
    bf16x2 o2;
    o2[0] = (__bf16)gelu_f(s0 * inv);
    o2[1] = (__bf16)gelu_f(s1 * inv);
    *(bf16x2*)(outb + (size_t)i * 128 + 2 * lane) = o2;
}

extern "C" void kernel_launch(void* const* d_in, const int* in_sizes, int n_in,
                              void* d_out, int out_size, void* d_ws, size_t ws_size,
                              hipStream_t stream) {
    const int N = N_NODES, E = N_EDGES;
    const int* node_attr = (const int*)d_in[0];
    const int* batch_idx = (const int*)d_in[1];
    const int* edge_index = (const int*)d_in[2];
    const int* strat_dist = (const int*)d_in[3];
    const int* strat_path = (const int*)d_in[4];
    const float* atom_emb = (const float*)d_in[5];
    const float* dist_emb = (const float*)d_in[6];
    const float* path_emb = (const float*)d_in[7];
    const float* Wq = (const float*)d_in[8];
    const float* bq = (const float*)d_in[9];
    const float* Wk = (const float*)d_in[10];
    const float* bk = (const float*)d_in[11];
    const float* Wv = (const float*)d_in[12];
    const float* bv = (const float*)d_in[13];
    const float* Wa = (const float*)d_in[14];
    const float* ba = (const float*)d_in[15];
    const float* ln1g = (const float*)d_in[16];
    const float* ln1b = (const float*)d_in[17];
    const float* Wmid = (const float*)d_in[18];
    const float* bmid = (const float*)d_in[19];
    const float* Wo = (const float*)d_in[20];
    const float* bo = (const float*)d_in[21];
    const float* ln2g = (const float*)d_in[22];
    const float* ln2b = (const float*)d_in[23];
    const float* Wout = (const float*)d_in[24];
    const float* bout = (const float*)d_in[25];
    float* out = (float*)d_out;

    const int* src = edge_index;
    const int* tgt = edge_index + E;

    // ---- workspace layout ----
    size_t NF = (size_t)N * HID;          // 6.4e6
    float* invc = (float*)d_ws;           // 256
    float* bqkv = invc + 256;             // 768
    __bf16* xb = (__bf16*)(bqkv + 768);   // NF
    __bf16* Qb = xb + NF;                 // NF
    __bf16* ab = Qb + NF;                 // NF: gelu(aggr) from attn
    __bf16* tkv = ab + NF;                // 2 * 512*256 bf16
    __bf16* wqkvf = tkv + 262144;         // 2*49152
    __bf16* waf = wqkvf + 98304;          // 2*16384
    __bf16* wmidf = waf + 32768;          // 2*32768
    __bf16* wof = wmidf + 65536;          // 2*32768
    uint8_t* kv8 = (uint8_t*)(wof + 65536);     // N*256 bytes fp8 (K|V)
    uint32_t* ei = (uint32_t*)(kv8 + (size_t)N * 256);  // N_PAD*CAP packed
    uint32_t* pack = ei + (size_t)N_PAD * CAP;  // E packed edge payloads
    int* cnt = (int*)(pack + N_EDGES);          // N (binning writes all entries)
    uint16_t* t16 = (uint16_t*)(cnt + N_NODES); // E u16 targets

    // ---- prep0 (repack + setup + packs), then prep1 (bin + enc + tkv) ----
    prep0_kernel<<<PREP0_B, 256, 0, stream>>>(
        Wq, Wa, Wmid, Wo, Wk, Wv, wqkvf, waf, wmidf, wof,
        batch_idx, bout, bq, bk, bv, invc, out, bqkv,
        src, strat_dist, strat_path, tgt, pack, t16);
    prep1_kernel<<<PREP1_B, 1024, 0, stream>>>(
        node_attr, atom_emb, xb, dist_emb, path_emb, Wk, Wv, tkv,
        t16, pack, cnt, ei);

    const int GB = (N + 63) / 64;   // 782 row-blocks
    const int AB = (N + 3) / 4;     // 12500 attn blocks (1 node/wave)

    for (int l = 0; l < NLAYER; ++l) {
        // fused QKV (pure GEMM)
        qkv_gemm<<<3 * GB, 256, 0, stream>>>(
            xb, wqkvf + l * 49152, bqkv + l * 384, Qb, kv8, N);

        // segment-softmax attention; writes gelu(aggr) bf16 into ab
        attn_kernel<<<AB, 256, 0, stream>>>(Qb, kv8, tkv + l * 131072, cnt, ei, ab);

        // uber FFN: h = LN1(ab@Wa + ba + xb); mid = gelu(h@Wmid); x = LN2(mid@Wo + h)
        if (l < NLAYER - 1) {
            ffn_uber<false><<<GB, 256, 0, stream>>>(
                ab, xb, waf + l * 16384, ba + l * 128, ln1g + l * 128, ln1b + l * 128,
                wmidf + l * 32768, bmid + l * 256, wof + l * 32768, bo + l * 128,
                ln2g + l * 128, ln2b + l * 128, xb,
                nullptr, nullptr, nullptr, nullptr, N);
        } else {
            ffn_uber<true><<<GB, 256, 0, stream>>>(
                ab, xb, waf + l * 16384, ba + l * 128, ln1g + l * 128, ln1b + l * 128,
                wmidf + l * 32768, bmid + l * 256, wof + l * 32768, bo + l * 128,
                ln2g + l * 128, ln2b + l * 128, nullptr,
                batch_idx, invc, Wout, out, N);
        }
    }
}

// Round 12
// 364.613 us; speedup vs baseline: 1.2991x; 1.2991x over previous
//
#include <hip/hip_runtime.h>
#include <hip/hip_bf16.h>
#include <math.h>
#include <stdint.h>

#define N_NODES 50000
#define N_EDGES 800000
#define HID 128
#define NGRAPH 256
#define NLAYER 2
#define CAP 64  // CSR slots per node; Poisson(16) tail beyond 64 ~ 1e-18

// XCD-local scatter (R8): 8 consecutive blocks share a 4096-edge window; block
// b handles targets in partition (b&7). cnt is PACKED (R12: padding removed —
// R8 counters showed the atomic cost is per-RMW line traffic, which padding
// maximizes; packed cnt = 200KB, L2-resident, single-XCD lines).
#define SC_GRP 196                    // ceil(800000/4096) edge windows
#define SC_B (SC_GRP * 8)             // 1568 scatter blocks
#define NPART 6250                    // nodes per partition (50000/8)

// prep section boundaries (after SC_B scatter blocks)
#define ENC_B 3125                    // encoder: 800000 threads, 8 ch each
#define TKV_B (ENC_B + 1024)          // 4149
#define RPK_B (TKV_B + 128)           // 4277
#define PREP_B (RPK_B + 4)            // 4281

typedef __bf16 bf16x8 __attribute__((ext_vector_type(8)));
typedef __bf16 bf16x2 __attribute__((ext_vector_type(2)));
typedef float f32x4 __attribute__((ext_vector_type(4)));
typedef float f32x2 __attribute__((ext_vector_type(2)));

__device__ __forceinline__ float gelu_f(float v) {
    return 0.5f * v * (1.0f + erff(v * 0.70710678118654752f));
}

// fp8 e4m3 (OCP on gfx950) helpers — cvt_pk returns a natural f32 pair
__device__ __forceinline__ f32x2 f8lo(uint32_t d) {
    return __builtin_amdgcn_cvt_pk_f32_fp8((int)d, false);
}
__device__ __forceinline__ f32x2 f8hi(uint32_t d) {
    return __builtin_amdgcn_cvt_pk_f32_fp8((int)d, true);
}
__device__ __forceinline__ uint32_t pk4_fp8(float a, float b, float c, float d) {
    int w = __builtin_amdgcn_cvt_pk_fp8_f32(a, b, 0, false);
    w = __builtin_amdgcn_cvt_pk_fp8_f32(c, d, w, true);
    return (uint32_t)w;
}
// bf16 pair (one dword) -> f32 pair. lo: shift. hi: reinterpret the dword
// directly — low 16 garbage bits contribute < 1 bf16 ulp.
__device__ __forceinline__ f32x2 bfpair(uint32_t d) {
    f32x2 r;
    r[0] = __uint_as_float(d << 16);
    r[1] = __uint_as_float(d);
    return r;
}

// ---------------- prep: XCD-local scatter | encoder | tkv | repack | setup -------
__global__ __launch_bounds__(256) void prep_kernel(
    const int* __restrict__ attr, const float* __restrict__ aemb,
    __bf16* __restrict__ xb,
    const float* __restrict__ de, const float* __restrict__ pe,
    const float* __restrict__ Wk, const float* __restrict__ Wv,
    __bf16* __restrict__ tkv,
    const float* __restrict__ Wq, const float* __restrict__ Wa,
    const float* __restrict__ Wmid, const float* __restrict__ Wo,
    __bf16* __restrict__ wqkvf, __bf16* __restrict__ waf,
    __bf16* __restrict__ wmidf, __bf16* __restrict__ wof,
    const int* __restrict__ batch, const float* __restrict__ bout,
    const float* __restrict__ bq, const float* __restrict__ bk,
    const float* __restrict__ bv,
    float* __restrict__ invc, float* __restrict__ outp, float* __restrict__ bqkv,
    const int* __restrict__ tgt, const int* __restrict__ src,
    const int* __restrict__ sd, const int* __restrict__ sp,
    int* __restrict__ cnt, uint32_t* __restrict__ ei) {
    __shared__ float sde[128];
    int b = blockIdx.x;
    int tid = threadIdx.x;
    if (b < SC_B) {
        // ---- CSR scatter, XCD-partitioned, packed counters ----
        int grp = b >> 3;
        int part = b & 7;            // round-robin -> XCD id (heuristic)
        int plo = part * NPART;
        int phi = plo + NPART;
        int base = grp * 4096 + tid;
#pragma unroll
        for (int k = 0; k < 16; k++) {
            int e = base + k * 256;
            if (e < N_EDGES) {
                int t = tgt[e];
                if (t >= plo && t < phi) {
                    uint32_t pk = (uint32_t)src[e] | ((uint32_t)((sd[e] << 4) | sp[e]) << 16);
                    int r = atomicAdd(&cnt[t], 1);
                    if (r < CAP) ei[(t << 6) + r] = pk;
                }
            }
        }
        return;
    }
    b -= SC_B;
    if (b < ENC_B) {
        // ---- node encoder: 8 channels/thread, float4 table reads ----
        int gid = b * 256 + tid;      // [0, 800000) = 50000 nodes * 16 groups
        int n = gid >> 4;
        int c8 = (gid & 15) << 3;
        const int4 a = *(const int4*)(attr + n * 4);
        const float* r0 = aemb + (size_t)(0 * 64 + a.x) * 128 + c8;
        const float* r1 = aemb + (size_t)(1 * 64 + a.y) * 128 + c8;
        const float* r2 = aemb + (size_t)(2 * 64 + a.z) * 128 + c8;
        const float* r3 = aemb + (size_t)(3 * 64 + a.w) * 128 + c8;
        f32x4 v0a = *(const f32x4*)r0, v0b = *(const f32x4*)(r0 + 4);
        f32x4 v1a = *(const f32x4*)r1, v1b = *(const f32x4*)(r1 + 4);
        f32x4 v2a = *(const f32x4*)r2, v2b = *(const f32x4*)(r2 + 4);
        f32x4 v3a = *(const f32x4*)r3, v3b = *(const f32x4*)(r3 + 4);
        bf16x8 o;
#pragma unroll
        for (int j = 0; j < 4; j++) {
            o[j] = (__bf16)(v0a[j] + v1a[j] + v2a[j] + v3a[j]);
            o[4 + j] = (__bf16)(v0b[j] + v1b[j] + v2b[j] + v3b[j]);
        }
        *(bf16x8*)(xb + (size_t)n * 128 + c8) = o;
    } else if (b < TKV_B) {
        // ---- combined relational tables (both layers), bf16 output ----
        int bb = b - ENC_B;
        int l = bb >> 9;
        int md = bb & 511;
        int dd = md >> 4, pp = md & 15;
        int c = tid;
        if (c < 128) sde[c] = de[l * 4096 + dd * 128 + c] + pe[l * 2048 + pp * 128 + c];
        __syncthreads();
        const float* W = (c < 128) ? (Wk + l * 16384) : (Wv + l * 16384);
        int cc = c & 127;
        float acc = 0.f;
#pragma unroll 4
        for (int k = 0; k < 128; k++) acc = fmaf(sde[k], W[k * 128 + cc], acc);
        tkv[(size_t)bb * 256 + c] = (__bf16)acc;
    } else if (b < RPK_B) {
        // ---- weight repack: fp32 [CI][CO] -> bf16 fragment units, sigma perm ----
        int u = (b - TKV_B) * 256 + tid;
        int l = u >> 14, r = u & 16383;
        const float* srcp;
        __bf16* dstp;
        int kg, scol, srcCO;
        if (r < 6144) {  // fused QKV, CO=384
            kg = r / 384;
            int uu = r % 384;
            int sec = uu >> 7, cc = uu & 127;
            scol = ((cc & 15) << 3) | (cc >> 4);
            const float* Ws = (sec == 0) ? Wq : (sec == 1) ? Wk : Wv;
            srcp = Ws + l * 16384;
            srcCO = 128;
            dstp = wqkvf + (size_t)l * 49152 + (size_t)r * 8;
        } else if (r < 8192) {  // Wa
            int rr = r - 6144;
            kg = rr >> 7;
            int cc = rr & 127;
            scol = ((cc & 15) << 3) | (cc >> 4);
            srcp = Wa + l * 16384;
            srcCO = 128;
            dstp = waf + (size_t)l * 16384 + (size_t)rr * 8;
        } else if (r < 12288) {  // Wmid, CO=256
            int rr = r - 8192;
            kg = rr >> 8;
            int uu = rr & 255;
            int blk = uu >> 7, cc = uu & 127;
            scol = blk * 128 + (((cc & 15) << 3) | (cc >> 4));
            srcp = Wmid + l * 32768;
            srcCO = 256;
            dstp = wmidf + (size_t)l * 32768 + (size_t)rr * 8;
        } else {  // Wo, CI=256
            int rr = r - 12288;
            kg = rr >> 7;
            int cc = rr & 127;
            scol = ((cc & 15) << 3) | (cc >> 4);
            srcp = Wo + l * 32768;
            srcCO = 128;
            dstp = wof + (size_t)l * 32768 + (size_t)rr * 8;
        }
        bf16x8 o;
#pragma unroll
        for (int j = 0; j < 8; j++) o[j] = (__bf16)srcp[(kg * 8 + j) * srcCO + scol];
        *(bf16x8*)dstp = o;
    } else {
        // ---- setup: per-graph invc + out init, fused QKV bias ----
        int sb = b - RPK_B;
        if (sb == 0) {
            int g = tid;
            int lo = 0, hi = N_NODES;
            while (lo < hi) { int mid = (lo + hi) >> 1; if (batch[mid] < g) lo = mid + 1; else hi = mid; }
            int start = lo;
            lo = start; hi = N_NODES;
            while (lo < hi) { int mid = (lo + hi) >> 1; if (batch[mid] < g + 1) lo = mid + 1; else hi = mid; }
            int c2 = lo - start;
            invc[g] = 1.0f / fmaxf((float)c2, 1.0f);
            outp[g] = bout[0];
        } else {
            int r = (sb - 1) * 256 + tid;
            int l = r / 384, c = r % 384;
            float v = (c < 128) ? bq[l * 128 + c]
                    : (c < 256) ? bk[l * 128 + c - 128]
                                : bv[l * 128 + c - 256];
            bqkv[r] = v;
        }
    }
}

// ---------------- QKV GEMM (pure) -------------------------------------------------
__global__ __launch_bounds__(256) void qkv_gemm(
    const __bf16* __restrict__ A, const __bf16* __restrict__ Wf,
    const float* __restrict__ bias, __bf16* __restrict__ Qb,
    uint8_t* __restrict__ kv8, int M) {
    int tid = threadIdx.x;
    int bq = blockIdx.x;
    int sec = bq % 3;           // consecutive blocks share A rows -> L2 reuse
    int rowblk = bq / 3;
    int lane = tid & 63;
    int wv = tid >> 6;
    int row0 = rowblk * 64 + wv * 16;
    int col0 = sec * 128;
    if (row0 >= M) return;
    int quad = lane >> 4, tq = lane & 15;
    f32x4 acc[8] = {};
#pragma unroll
    for (int k0 = 0; k0 < 128; k0 += 32) {
        int rr = row0 + tq;
        if (rr >= M) rr = M - 1;
        bf16x8 af = *(const bf16x8*)(A + (size_t)rr * 128 + k0 + quad * 8);
#pragma unroll
        for (int nt = 0; nt < 8; nt++) {
            bf16x8 bfr = *(const bf16x8*)(Wf + ((size_t)((k0 >> 3) + quad) * 384 + col0 + nt * 16 + tq) * 8);
            acc[nt] = __builtin_amdgcn_mfma_f32_16x16x32_bf16(af, bfr, acc[nt], 0, 0, 0);
        }
    }
    int cb = tq * 8;
    float bia[8];
#pragma unroll
    for (int t = 0; t < 8; t++) bia[t] = bias[col0 + cb + t];
#pragma unroll
    for (int v = 0; v < 4; v++) {
        int rr = row0 + quad * 4 + v;
        if (rr >= M) continue;
        float val[8];
#pragma unroll
        for (int t = 0; t < 8; t++) val[t] = acc[t][v] + bia[t];
        if (sec == 0) {
            bf16x8 ov;
#pragma unroll
            for (int t = 0; t < 8; t++) ov[t] = (__bf16)val[t];
            *(bf16x8*)(Qb + (size_t)rr * 128 + cb) = ov;
        } else {
            uint2 st;
            st.x = pk4_fp8(val[0], val[1], val[2], val[3]);
            st.y = pk4_fp8(val[4], val[5], val[6], val[7]);
            *(uint2*)(kv8 + (size_t)rr * 256 + (sec - 1) * 128 + cb) = st;
        }
    }
}

// ---------------- uber FFN: h=LN1(aggr@Wa+ba+x); mid=gelu(h@Wmid); x=LN2(mid@Wo+h)
template <bool POOL>
__global__ __launch_bounds__(256) void ffn_uber(
    const __bf16* __restrict__ A,      // gelu(aggr), N x 128
    const __bf16* __restrict__ xres,   // x (LN1 residual), N x 128
    const __bf16* __restrict__ Waf, const float* __restrict__ ba,
    const float* __restrict__ l1g, const float* __restrict__ l1b,
    const __bf16* __restrict__ Wmf, const float* __restrict__ bmid,
    const __bf16* __restrict__ Wof, const float* __restrict__ bo,
    const float* __restrict__ l2g, const float* __restrict__ l2b,
    __bf16* __restrict__ outx,
    const int* __restrict__ batch, const float* __restrict__ invc,
    const float* __restrict__ WoutV, float* __restrict__ outp,
    int M) {
    __shared__ __bf16 hld[4][16][136];   // per-wave 16x128 h tile, +8 row pad
    __shared__ __bf16 smid[4][16][264];  // per-wave 16x256 mid tile, +8 row pad
    __shared__ float ps[POOL ? NGRAPH : 1];
    int lane = threadIdx.x & 63;
    int wv = threadIdx.x >> 6;
    int row0 = blockIdx.x * 64 + wv * 16;
    bool active = row0 < M;
    if (POOL) {
        ps[threadIdx.x] = 0.f;
        __syncthreads();
    } else if (!active) {
        return;
    }
    int quad = lane >> 4, tq = lane & 15;
    if (active) {
        int cb = tq * 8;
        // ---- phase 0: h = LN1(aggr@Wa + ba + x) -> hld ----
        {
            f32x4 acc[8] = {};
#pragma unroll
            for (int k0 = 0; k0 < 128; k0 += 32) {
                int rr = row0 + tq;
                if (rr >= M) rr = M - 1;
                bf16x8 af = *(const bf16x8*)(A + (size_t)rr * 128 + k0 + quad * 8);
#pragma unroll
                for (int nt = 0; nt < 8; nt++) {
                    bf16x8 bfr = *(const bf16x8*)(Waf + ((size_t)((k0 >> 3) + quad) * 128 + nt * 16 + tq) * 8);
                    acc[nt] = __builtin_amdgcn_mfma_f32_16x16x32_bf16(af, bfr, acc[nt], 0, 0, 0);
                }
            }
            float bia[8], gv[8], bv2[8];
#pragma unroll
            for (int t = 0; t < 8; t++) {
                bia[t] = ba[cb + t];
                gv[t] = l1g[cb + t];
                bv2[t] = l1b[cb + t];
            }
#pragma unroll
            for (int v = 0; v < 4; v++) {
                int rr = row0 + quad * 4 + v;
                int rc = (rr < M) ? rr : M - 1;
                bf16x8 rv = *(const bf16x8*)(xres + (size_t)rc * 128 + cb);
                float val[8];
#pragma unroll
                for (int t = 0; t < 8; t++) val[t] = acc[t][v] + bia[t] + (float)rv[t];
                float s = 0.f, s2 = 0.f;
#pragma unroll
                for (int t = 0; t < 8; t++) { s += val[t]; s2 = fmaf(val[t], val[t], s2); }
#pragma unroll
                for (int o = 1; o < 16; o <<= 1) {
                    s += __shfl_xor(s, o);
                    s2 += __shfl_xor(s2, o);
                }
                float m = s * (1.0f / 128.0f);
                float var = s2 * (1.0f / 128.0f) - m * m;
                float rs = rsqrtf(var + 1e-5f);
                bf16x8 ov;
#pragma unroll
                for (int t = 0; t < 8; t++) ov[t] = (__bf16)((val[t] - m) * rs * gv[t] + bv2[t]);
                *(bf16x8*)(&hld[wv][quad * 4 + v][cb]) = ov;
            }
        }
        asm volatile("" ::: "memory");  // keep ds_reads after ds_writes (in-order DS)
        // ---- phase 1: mid = gelu(h@Wmid + bmid) -> smid ----
#pragma unroll
        for (int cH = 0; cH < 2; ++cH) {
            f32x4 acc[8] = {};
#pragma unroll
            for (int k0 = 0; k0 < 128; k0 += 32) {
                bf16x8 af = *(const bf16x8*)(&hld[wv][tq][k0 + quad * 8]);
#pragma unroll
                for (int nt = 0; nt < 8; nt++) {
                    bf16x8 bfr = *(const bf16x8*)(Wmf + ((size_t)((k0 >> 3) + quad) * 256 + cH * 128 + nt * 16 + tq) * 8);
                    acc[nt] = __builtin_amdgcn_mfma_f32_16x16x32_bf16(af, bfr, acc[nt], 0, 0, 0);
                }
            }
            int cb2 = cH * 128 + cb;
            float bia[8];
#pragma unroll
            for (int t = 0; t < 8; t++) bia[t] = bmid[cb2 + t];
#pragma unroll
            for (int v = 0; v < 4; v++) {
                bf16x8 ov;
#pragma unroll
                for (int t = 0; t < 8; t++) ov[t] = (__bf16)gelu_f(acc[t][v] + bia[t]);
                *(bf16x8*)(&smid[wv][quad * 4 + v][cb2]) = ov;
            }
        }
        asm volatile("" ::: "memory");
        // ---- phase 2: x = LN2(mid@Wo + bo + h) ----
        f32x4 acc[8] = {};
#pragma unroll
        for (int k0 = 0; k0 < 256; k0 += 32) {
            bf16x8 af = *(const bf16x8*)(&smid[wv][tq][k0 + quad * 8]);
#pragma unroll
            for (int nt = 0; nt < 8; nt++) {
                bf16x8 bfr = *(const bf16x8*)(Wof + ((size_t)((k0 >> 3) + quad) * 128 + nt * 16 + tq) * 8);
                acc[nt] = __builtin_amdgcn_mfma_f32_16x16x32_bf16(af, bfr, acc[nt], 0, 0, 0);
            }
        }
        float bia[8], gv[8], bv2[8], wo8[8];
#pragma unroll
        for (int t = 0; t < 8; t++) {
            bia[t] = bo[cb + t];
            gv[t] = l2g[cb + t];
            bv2[t] = l2b[cb + t];
        }
        if (POOL) {
#pragma unroll
            for (int t = 0; t < 8; t++) wo8[t] = WoutV[cb + t];
        }
#pragma unroll
        for (int v = 0; v < 4; v++) {
            int rr = row0 + quad * 4 + v;
            bf16x8 rv = *(const bf16x8*)(&hld[wv][quad * 4 + v][cb]);  // residual h
            float val[8];
#pragma unroll
            for (int t = 0; t < 8; t++) val[t] = acc[t][v] + bia[t] + (float)rv[t];
            float s = 0.f, s2 = 0.f;
#pragma unroll
            for (int t = 0; t < 8; t++) { s += val[t]; s2 = fmaf(val[t], val[t], s2); }
#pragma unroll
            for (int o = 1; o < 16; o <<= 1) {
                s += __shfl_xor(s, o);
                s2 += __shfl_xor(s2, o);
            }
            float m = s * (1.0f / 128.0f);
            float var = s2 * (1.0f / 128.0f) - m * m;
            float rs = rsqrtf(var + 1e-5f);
#pragma unroll
            for (int t = 0; t < 8; t++) val[t] = (val[t] - m) * rs * gv[t] + bv2[t];
            if (rr >= M) continue;
            if (!POOL) {
                bf16x8 ov;
#pragma unroll
                for (int t = 0; t < 8; t++) ov[t] = (__bf16)val[t];
                *(bf16x8*)(outx + (size_t)rr * 128 + cb) = ov;
            } else {
                float dot = 0.f;
#pragma unroll
                for (int t = 0; t < 8; t++) dot = fmaf(val[t], wo8[t], dot);
#pragma unroll
                for (int o = 1; o < 16; o <<= 1) dot += __shfl_xor(dot, o);
                if (tq == 0) {
                    int g = batch[rr];
                    atomicAdd(&ps[g], dot * invc[g]);  // LDS atomic: fast, per-CU
                }
            }
        }
    }
    if (POOL) {
        __syncthreads();
        float pv = ps[threadIdx.x];
        if (pv != 0.f) atomicAdd(&outp[threadIdx.x], pv);
    }
}

// ---------------- attention: one wave per node, 8 edges in flight, 1 head/lane ----
// CAP-CSR; fp8 K/V; bf16 tkv; 2-deep pipeline; packed-f32 (v_pk_*) inner math.
// R12: slot-merge via 3-round __shfl_xor butterfly (slot = lane bits 3-5) —
// zero LDS, zero bank conflicts (was 1.7M/dispatch).
__global__ __launch_bounds__(256) void attn_kernel(
    const __bf16* __restrict__ Qb, const uint8_t* __restrict__ kv8,
    const __bf16* __restrict__ tkv,
    const int* __restrict__ cnt, const uint32_t* __restrict__ ei,
    __bf16* __restrict__ outb) {
    int wv = threadIdx.x >> 6;
    int i = blockIdx.x * 4 + wv;  // N = 50000 = 12500*4: no tail
    int lane = threadIdx.x & 63;
    int slot = lane >> 3, h = lane & 7;
    int ch0 = h * 16;
    // q as 8 packed f32 pairs (fixed cost, out of loop)
    const uint4* qv = (const uint4*)(Qb + (size_t)i * 128 + ch0);
    uint4 qa = qv[0], qb = qv[1];
    uint32_t qd[8] = {qa.x, qa.y, qa.z, qa.w, qb.x, qb.y, qb.z, qb.w};
    f32x2 qp[8];
#pragma unroll
    for (int j = 0; j < 8; j++) qp[j] = bfpair(qd[j]);
    int deg = cnt[i];
    if (deg > CAP) deg = CAP;
    int p0 = i << 6;
    int p1 = p0 + deg;
    float l = 0.f;
    f32x2 ap[8] = {};
    int p = p0 + slot;
    uint32_t w1 = 0, w2 = 0;
    if (p < p1) w1 = ei[p];
    if (p + 8 < p1) w2 = ei[p + 8];
    uint4 kw, vw, t0, t1, u0, u1;
    {
        int j = w1 & 0xffff, md = w1 >> 16;
        const uint8_t* kr = kv8 + (size_t)j * 256 + ch0;
        kw = *(const uint4*)kr;
        vw = *(const uint4*)(kr + 128);
        const __bf16* tr = tkv + md * 256 + ch0;
        t0 = *(const uint4*)tr;
        t1 = *(const uint4*)(tr + 8);
        u0 = *(const uint4*)(tr + 128);
        u1 = *(const uint4*)(tr + 136);
    }
    while (p < p1) {
        uint4 kwn, vwn, t0n, t1n, u0n, u1n;
        {
            int j = w2 & 0xffff, md = w2 >> 16;
            const uint8_t* kr = kv8 + (size_t)j * 256 + ch0;
            kwn = *(const uint4*)kr;
            vwn = *(const uint4*)(kr + 128);
            const __bf16* tr = tkv + md * 256 + ch0;
            t0n = *(const uint4*)tr;
            t1n = *(const uint4*)(tr + 8);
            u0n = *(const uint4*)(tr + 128);
            u1n = *(const uint4*)(tr + 136);
        }
        // unconditional clamped prefetch (no exec-mask branch in the loop)
        int pn = p + 16;
        uint32_t w3 = ei[(pn < p1) ? pn : p];
        uint32_t kd[4] = {kw.x, kw.y, kw.z, kw.w};
        uint32_t vd[4] = {vw.x, vw.y, vw.z, vw.w};
        uint32_t td[8] = {t0.x, t0.y, t0.z, t0.w, t1.x, t1.y, t1.z, t1.w};
        uint32_t ud[8] = {u0.x, u0.y, u0.z, u0.w, u1.x, u1.y, u1.z, u1.w};
        f32x2 sa = {0.f, 0.f};
#pragma unroll
        for (int j = 0; j < 4; j++) {
            f32x2 klo = f8lo(kd[j]) + bfpair(td[2 * j]);
            f32x2 khi = f8hi(kd[j]) + bfpair(td[2 * j + 1]);
            sa = qp[2 * j] * klo + sa;       // v_pk_fma_f32
            sa = qp[2 * j + 1] * khi + sa;
        }
        float s = sa[0] + sa[1];
        float pe = __expf(s * 0.25f);  // 1/sqrt(DK)
        l += pe;
        f32x2 pp = {pe, pe};
#pragma unroll
        for (int j = 0; j < 4; j++) {
            f32x2 vlo = f8lo(vd[j]) + bfpair(ud[2 * j]);
            f32x2 vhi = f8hi(vd[j]) + bfpair(ud[2 * j + 1]);
            ap[2 * j] = pp * vlo + ap[2 * j];
            ap[2 * j + 1] = pp * vhi + ap[2 * j + 1];
        }
        kw = kwn; vw = vwn; t0 = t0n; t1 = t1n; u0 = u0n; u1 = u1n;
        w2 = w3;
        p += 8;
    }
    // ---- slot-merge: butterfly over lane bits 3-5 (slots), per head ----
#pragma unroll
    for (int m = 8; m <= 32; m <<= 1) {
        l += __shfl_xor(l, m);
#pragma unroll
        for (int j = 0; j < 8; j++) {
            f32x2 o;
            o[0] = __shfl_xor(ap[j][0], m);
            o[1] = __shfl_xor(ap[j][1], m);
            ap[j] = ap[j] + o;
        }
    }
    float inv = 1.0f / (l + 1e-16f);
    // lane (slot,h) writes channel pair (h*16 + slot*2). Static select of
    // ap[slot] via cndmask chain (runtime vector index would spill).
    float v0 = ap[0][0], v1 = ap[0][1];
#pragma unroll
    for (int j = 1; j < 8; j++) {
        if (slot == j) { v0 = ap[j][0]; v1 = ap[j][1]; }
    }
    bf16x2 o2;
    o2[0] = (__bf16)gelu_f(v0 * inv);
    o2[1] = (__bf16)gelu_f(v1 * inv);
    *(bf16x2*)(outb + (size_t)i * 128 + ch0 + slot * 2) = o2;
}

extern "C" void kernel_launch(void* const* d_in, const int* in_sizes, int n_in,
                              void* d_out, int out_size, void* d_ws, size_t ws_size,
                              hipStream_t stream) {
    const int N = N_NODES, E = N_EDGES;
    const int* node_attr = (const int*)d_in[0];
    const int* batch_idx = (const int*)d_in[1];
    const int* edge_index = (const int*)d_in[2];
    const int* strat_dist = (const int*)d_in[3];
    const int* strat_path = (const int*)d_in[4];
    const float* atom_emb = (const float*)d_in[5];
    const float* dist_emb = (const float*)d_in[6];
    const float* path_emb = (const float*)d_in[7];
    const float* Wq = (const float*)d_in[8];
    const float* bq = (const float*)d_in[9];
    const float* Wk = (const float*)d_in[10];
    const float* bk = (const float*)d_in[11];
    const float* Wv = (const float*)d_in[12];
    const float* bv = (const float*)d_in[13];
    const float* Wa = (const float*)d_in[14];
    const float* ba = (const float*)d_in[15];
    const float* ln1g = (const float*)d_in[16];
    const float* ln1b = (const float*)d_in[17];
    const float* Wmid = (const float*)d_in[18];
    const float* bmid = (const float*)d_in[19];
    const float* Wo = (const float*)d_in[20];
    const float* bo = (const float*)d_in[21];
    const float* ln2g = (const float*)d_in[22];
    const float* ln2b = (const float*)d_in[23];
    const float* Wout = (const float*)d_in[24];
    const float* bout = (const float*)d_in[25];
    float* out = (float*)d_out;

    const int* src = edge_index;
    const int* tgt = edge_index + E;

    // ---- workspace layout ----
    size_t NF = (size_t)N * HID;          // 6.4e6
    float* invc = (float*)d_ws;           // 256
    float* bqkv = invc + 256;             // 768
    __bf16* xb = (__bf16*)(bqkv + 768);   // NF
    __bf16* Qb = xb + NF;                 // NF
    __bf16* ab = Qb + NF;                 // NF: gelu(aggr) from attn
    __bf16* tkv = ab + NF;                // 2 * 512*256 bf16
    __bf16* wqkvf = tkv + 262144;         // 2*49152
    __bf16* waf = wqkvf + 98304;          // 2*16384
    __bf16* wmidf = waf + 32768;          // 2*32768
    __bf16* wof = wmidf + 65536;          // 2*32768
    uint8_t* kv8 = (uint8_t*)(wof + 65536);     // N*256 bytes fp8 (K|V)
    uint32_t* ei = (uint32_t*)(kv8 + (size_t)N * 256);  // N*CAP packed
    int* cnt = (int*)(ei + (size_t)N * CAP);    // N packed counters (200KB)

    // ---- prep (full XCD-local scatter + encoder + tkv + repack + setup) ----
    hipMemsetAsync(cnt, 0, (size_t)N * sizeof(int), stream);
    prep_kernel<<<SC_B + PREP_B, 256, 0, stream>>>(
        node_attr, atom_emb, xb,
        dist_emb, path_emb, Wk, Wv, tkv,
        Wq, Wa, Wmid, Wo, wqkvf, waf, wmidf, wof,
        batch_idx, bout, bq, bk, bv, invc, out, bqkv,
        tgt, src, strat_dist, strat_path, cnt, ei);

    const int GB = (N + 63) / 64;   // 782 row-blocks
    const int AB = (N + 3) / 4;     // 12500 attn blocks (1 node/wave)

    for (int l = 0; l < NLAYER; ++l) {
        // fused QKV (pure GEMM)
        qkv_gemm<<<3 * GB, 256, 0, stream>>>(
            xb, wqkvf + l * 49152, bqkv + l * 384, Qb, kv8, N);

        // segment-softmax attention; writes gelu(aggr) bf16 into ab
        attn_kernel<<<AB, 256, 0, stream>>>(Qb, kv8, tkv + l * 131072, cnt, ei, ab);

        // uber FFN: h = LN1(ab@Wa + ba + xb); mid = gelu(h@Wmid); x = LN2(mid@Wo + h)
        if (l < NLAYER - 1) {
            ffn_uber<false><<<GB, 256, 0, stream>>>(
                ab, xb, waf + l * 16384, ba + l * 128, ln1g + l * 128, ln1b + l * 128,
                wmidf + l * 32768, bmid + l * 256, wof + l * 32768, bo + l * 128,
                ln2g + l * 128, ln2b + l * 128, xb,
                nullptr, nullptr, nullptr, nullptr, N);
        } else {
            ffn_uber<true><<<GB, 256, 0, stream>>>(
                ab, xb, waf + l * 16384, ba + l * 128, ln1g + l * 128, ln1b + l * 128,
                wmidf + l * 32768, bmid + l * 256, wof + l * 32768, bo + l * 128,
                ln2g + l * 128, ln2b + l * 128, nullptr,
                batch_idx, invc, Wout, out, N);
        }
    }
}